// Round 8
// baseline (53.702 us; speedup 1.0000x reference)
//
#include <hip/hip_runtime.h>

typedef _Float16 f16;
typedef _Float16 f16x2 __attribute__((ext_vector_type(2)));
typedef _Float16 f16x4 __attribute__((ext_vector_type(4)));
typedef float    f32x4 __attribute__((ext_vector_type(4)));
typedef unsigned int u32;
typedef unsigned int u32x2v __attribute__((ext_vector_type(2)));

#define NS 2048
#define NH 16
#define NDK 8
#define NE 128
#define CHUNK 512
#define NCHUNK 4
// log2(e)/sqrt(8): exp(dot/sqrt(8)) == exp2(dot * CSCALE)
#define CSCALE 0.51006972f

__device__ __forceinline__ float fexp2(float v){
#if __has_builtin(__builtin_amdgcn_exp2f)
  return __builtin_amdgcn_exp2f(v);
#else
  return exp2f(v);
#endif
}

__device__ __forceinline__ f16x2 pkrtz(float a, float b){
  return __builtin_bit_cast(f16x2, __builtin_amdgcn_cvt_pkrtz(a, b));
}

__device__ __forceinline__ float fdot2a(f16x2 a, f16x2 b, float c){
#if __has_builtin(__builtin_amdgcn_fdot2)
  return __builtin_amdgcn_fdot2(a, b, c, false);
#else
  return c + (float)a[0]*(float)b[0] + (float)a[1]*(float)b[1];
#endif
}

// async global->LDS, 16B per lane, dest = wave-uniform base + lane*16
#define GLOAD16(g, l) __builtin_amdgcn_global_load_lds( \
    (const __attribute__((address_space(1))) u32*)(g), \
    (__attribute__((address_space(3))) u32*)(l), 16, 0, 0)

// ---------------------------------------------------------------------------
// qcos: compute cos(x+theta) once, emit TWO f16 layouts:
//  kbuf[(b*16+h)*2048 + s]       : 16B per key (K-layout; also Q source)
//  vbuf[bh][tile t][d][grp][i]   : 16B granule-pairs; byte off within tile
//                                  = d*32 + gp*16, u16 j = key 16t+8gp+j
// Block = one (b, tile): 256 thr = 16 keys x 16 heads; LDS transpose.
// ---------------------------------------------------------------------------
__global__ __launch_bounds__(256) void qcos(const float* __restrict__ x,
                                            const float* __restrict__ theta,
                                            u32* __restrict__ kbuf,
                                            u32* __restrict__ vbuf){
  __shared__ __align__(16) uint4 Lt[16*17];   // [h][sl] pad 17 vs bank hits
  const int bid = blockIdx.x;
  const int b   = bid >> 7;
  const int t   = bid & 127;
  const int tid = threadIdx.x;

  const float4 thA = ((const float4*)theta)[0];
  const float4 thB = ((const float4*)theta)[1];

  // phase 1: key s = 16t + sl, head h -> 8 f16
  {
    const int sl = tid & 15, h = tid >> 4;
    const int s  = t*16 + sl;
    const float* xp = x + ((size_t)(b*NS + s)*NE + h*NDK);
    const float4 x0 = ((const float4*)xp)[0];
    const float4 x1 = ((const float4*)xp)[1];
    union { f16 hh[8]; uint4 u; } pk;
    pk.hh[0] = (f16)__cosf(x0.x + thA.x);
    pk.hh[1] = (f16)__cosf(x0.y + thA.y);
    pk.hh[2] = (f16)__cosf(x0.z + thA.z);
    pk.hh[3] = (f16)__cosf(x0.w + thA.w);
    pk.hh[4] = (f16)__cosf(x1.x + thB.x);
    pk.hh[5] = (f16)__cosf(x1.y + thB.y);
    pk.hh[6] = (f16)__cosf(x1.z + thB.z);
    pk.hh[7] = (f16)__cosf(x1.w + thB.w);
    ((uint4*)kbuf)[(size_t)(b*16 + h)*NS + s] = pk.u;
    Lt[h*17 + sl] = pk.u;
  }
  __syncthreads();

  // phase 2: V-tile layout. thread -> (h, d, gp): 16B = keys 8gp..8gp+7 @ dim d
  {
    const int h  = tid >> 4;
    const int d  = (tid >> 1) & 7;
    const int gp = tid & 1;
    const unsigned short* Ls = (const unsigned short*)Lt;
    union { unsigned short us[8]; uint4 u; } pk;
    #pragma unroll
    for(int j = 0; j < 8; ++j)
      pk.us[j] = Ls[(h*17 + 8*gp + j)*8 + d];
    ((uint4*)vbuf)[((size_t)(b*16 + h)*128 + t)*16 + d*2 + gp] = pk.u;
  }
}

// one QK->exp2->PV tile of 16 keys (plain C reads; compiler schedules waits)
#define QTILE(T, VPO, KPO, ACC) do{ \
    uint2 ka_ = (KPO)[(T)*32]; \
    uint2 va_ = (VPO)[(T)*32]; \
    f16x4 kf_ = __builtin_bit_cast(f16x4, ka_); \
    f16x4 vf_ = __builtin_bit_cast(f16x4, va_); \
    f32x4 st_ = __builtin_amdgcn_mfma_f32_16x16x16f16(kf_, qf, z4, 0, 0, 0); \
    f16x2 plo_ = pkrtz(fexp2(st_[0]), fexp2(st_[1])); \
    f16x2 phi_ = pkrtz(fexp2(st_[2]), fexp2(st_[3])); \
    u32x2v pu_ = { __builtin_bit_cast(u32, plo_), __builtin_bit_cast(u32, phi_) }; \
    f16x4 pf_ = __builtin_bit_cast(f16x4, pu_); \
    ACC = __builtin_amdgcn_mfma_f32_16x16x16f16(vf_, pf_, ACC, 0, 0, 0); \
  }while(0)

// ---------------------------------------------------------------------------
// qattn: grid 1024 = 64 (b,h) x 16 q-chunks of 128 rows; 512 thr (8 waves x
// 16 q-rows). K/V f16 streamed from kbuf/vbuf in 512-key chunks, double-
// buffered, staged via global_load_lds width-16 LINEARLY (vbuf is already in
// fragment order). PV A-fragment = one contiguous ds_read_b64 (2-way banks =
// free). Lanes c>=8 read a broadcast Ones region -> acc row 8 = denominator.
// ---------------------------------------------------------------------------
__global__ __launch_bounds__(512, 4) void qattn(const u32* __restrict__ kbuf,
                                                const u32* __restrict__ vbuf,
                                                float* __restrict__ out){
  __shared__ __align__(16) u32 Kc[2][2048];     // 2 x 8KB linear [key][16B]
  __shared__ __align__(16) u32 Vt[2][2048];     // 2 x 8KB tile-granule layout
  __shared__ __align__(16) u32 OnesR[512];      // 2KB f16 1.0

  const int bid  = blockIdx.x;
  const int bh   = bid >> 4;        // 0..63
  const int qc   = bid & 15;        // q-chunk of 128 rows
  const int tid  = threadIdx.x;
  const int lane = tid & 63;
  const int w    = tid >> 6;        // wave 0..7
  const int c    = lane & 15;
  const int grp  = lane >> 4;       // 0..3
  const int g1   = grp & 1;
  const bool lo32  = lane < 32;
  const bool creal = c < 8;

  const u32* kb = kbuf + (size_t)bh*8192;    // 2048 keys x 16B
  const u32* vb = vbuf + (size_t)bh*8192;    // 128 tiles x 256B  (R7 bug: was *2048)

  OnesR[tid] = 0x3C003C00u;   // 512 x 4B = 2KB of f16 1.0

  // ---- staging sources: linear, 16B per thread ----
  const u32* gk = kb + (size_t)tid*4;
  const u32* gv = vb + (size_t)tid*4;

  // ---- Q fragment: row qc*128 + w*16 + c, dims g1*4.., scaled by CSCALE ----
  const int qrow = qc*128 + w*16 + c;
  uint2 qv = make_uint2(0u, 0u);
  if(lo32) qv = *(const uint2*)(kb + (size_t)qrow*4 + g1*2);
  f16x4 q4 = __builtin_bit_cast(f16x4, qv);
  q4 *= (f16)CSCALE;
  const f16x4 qf = q4;

  // per-lane V read base (byte offset within a tile): d*32 + grp*8
  const u32 vlane = ((u32)(c & 7))*32u + ((u32)grp)*8u;
  const char* onesc = (const char*)OnesR;

  const f32x4 z4 = {0.f, 0.f, 0.f, 0.f};
  f32x4 acc0 = z4, acc1 = z4;

  // prologue: issue chunk 0 loads (each wave stages 1KB per buffer)
  GLOAD16(gk, &Kc[0][w*256]);
  GLOAD16(gv, &Vt[0][w*256]);

  for(int cc = 0; cc < NCHUNK; ++cc){
    __syncthreads();   // drains vmcnt(0), then barrier: chunk cc ready
    if(cc + 1 < NCHUNK){
      GLOAD16(gk + (size_t)(cc+1)*2048, &Kc[(cc+1)&1][w*256]);
      GLOAD16(gv + (size_t)(cc+1)*2048, &Vt[(cc+1)&1][w*256]);
    }
    const uint2* kp = (const uint2*)&Kc[cc&1][0] + c*2 + g1;
    const char*  vc = (const char*)&Vt[cc&1][0] + vlane;
    #pragma unroll
    for(int o = 0; o < 4; ++o){                       // 4 octets of 8 tiles
      const uint2* kpo = kp + o*256;
      const uint2* vpo = (const uint2*)(creal ? vc + o*2048 : onesc);
      QTILE(0, vpo, kpo, acc0);
      QTILE(1, vpo, kpo, acc1);
      QTILE(2, vpo, kpo, acc0);
      QTILE(3, vpo, kpo, acc1);
      QTILE(4, vpo, kpo, acc0);
      QTILE(5, vpo, kpo, acc1);
      QTILE(6, vpo, kpo, acc0);
      QTILE(7, vpo, kpo, acc1);
    }
  }

  // ---- epilogue: acc row 8 (lane 32+c, reg 0) = denominator for q=c ----
  f32x4 accT;
  accT[0] = acc0[0]+acc1[0]; accT[1] = acc0[1]+acc1[1];
  accT[2] = acc0[2]+acc1[2]; accT[3] = acc0[3]+acc1[3];
  const int b = bh >> 4, h = bh & 15;
  float den = __shfl(accT[0], 32 + c, 64);
  if(lo32){
    float inv = 1.0f / den;
    float4 o;
    o.x = accT[0]*inv; o.y = accT[1]*inv; o.z = accT[2]*inv; o.w = accT[3]*inv;
    // attn_out[b][q][h][d], d = 4*grp + r (d_out used as scratch)
    *(float4*)(out + ((size_t)(b*NS + qrow)*NH + h)*NDK + grp*4) = o;
  }
}

// ---------------------------------------------------------------------------
// Combine: out = attn @ W^T + bias, in-place on d_out (unchanged).
// ---------------------------------------------------------------------------
__global__ __launch_bounds__(256) void qcomb(const float* __restrict__ W,
                                             const float* __restrict__ bias,
                                             float* __restrict__ io){
  __shared__ __align__(16) u32 Wt[64*132];
  __shared__ __align__(16) u32 A2[32*65];
  const int tid = threadIdx.x;
  const size_t row0 = (size_t)blockIdx.x * 32;

  #pragma unroll
  for(int i=0;i<32;++i){
    int g = tid + 256*i;
    int j = g >> 6, e2 = g & 63;
    const float* wp = W + (size_t)j*NE + 2*e2;
    f16x2 wv = pkrtz(wp[0], wp[1]);
    Wt[e2*132 + j] = __builtin_bit_cast(u32, wv);
  }
  #pragma unroll
  for(int i=0;i<8;++i){
    int g = tid + 256*i;
    int r = g >> 6, e2 = g & 63;
    const float* ap = io + (row0 + r)*NE + 2*e2;
    f16x2 av = pkrtz(ap[0], ap[1]);
    A2[r*65 + e2] = __builtin_bit_cast(u32, av);
  }
  __syncthreads();

  const int tr = tid >> 4, tc = tid & 15;
  float acc0[8] = {0,0,0,0,0,0,0,0};
  float acc1[8] = {0,0,0,0,0,0,0,0};
  for(int e2=0; e2<64; ++e2){
    f16x2 a0 = __builtin_bit_cast(f16x2, A2[tr*65 + e2]);
    f16x2 a1 = __builtin_bit_cast(f16x2, A2[(tr+16)*65 + e2]);
    const u32* wr = &Wt[e2*132 + tc*8];
    #pragma unroll
    for(int cj=0; cj<8; ++cj){
      f16x2 wv = __builtin_bit_cast(f16x2, wr[cj]);
      acc0[cj] = fdot2a(a0, wv, acc0[cj]);
      acc1[cj] = fdot2a(a1, wv, acc1[cj]);
    }
  }

  float4 b0 = *(const float4*)(bias + tc*8);
  float4 b1 = *(const float4*)(bias + tc*8 + 4);
  float* o0 = io + (row0 + tr)*NE + tc*8;
  float* o1 = io + (row0 + tr + 16)*NE + tc*8;
  float4 v;
  v.x = acc0[0]+b0.x; v.y = acc0[1]+b0.y; v.z = acc0[2]+b0.z; v.w = acc0[3]+b0.w;
  *(float4*)(o0) = v;
  v.x = acc0[4]+b1.x; v.y = acc0[5]+b1.y; v.z = acc0[6]+b1.z; v.w = acc0[7]+b1.w;
  *(float4*)(o0+4) = v;
  v.x = acc1[0]+b0.x; v.y = acc1[1]+b0.y; v.z = acc1[2]+b0.z; v.w = acc1[3]+b0.w;
  *(float4*)(o1) = v;
  v.x = acc1[4]+b1.x; v.y = acc1[5]+b1.y; v.z = acc1[6]+b1.z; v.w = acc1[7]+b1.w;
  *(float4*)(o1+4) = v;
}

extern "C" void kernel_launch(void* const* d_in, const int* in_sizes, int n_in,
                              void* d_out, int out_size, void* d_ws, size_t ws_size,
                              hipStream_t stream) {
  (void)in_sizes; (void)n_in; (void)out_size; (void)ws_size;
  const float* x     = (const float*)d_in[0];
  const float* theta = (const float*)d_in[1];
  const float* W     = (const float*)d_in[2];
  const float* bias  = (const float*)d_in[3];
  float* out = (float*)d_out;
  u32* kbuf = (u32*)d_ws;            // 2MB: K/Q layout [bh][s][8 f16]
  u32* vbuf = kbuf + 524288;         // 2MB: V tile-granule layout

  qcos <<<512, 256, 0, stream>>>(x, theta, kbuf, vbuf);
  qattn<<<1024, 512, 0, stream>>>(kbuf, vbuf, out);
  qcomb<<<256, 256, 0, stream>>>(W, bias, out);
}

// Round 9
// 51.054 us; speedup vs baseline: 1.0519x; 1.0519x over previous
//
#include <hip/hip_runtime.h>

typedef _Float16 f16;
typedef _Float16 f16x2 __attribute__((ext_vector_type(2)));
typedef _Float16 f16x4 __attribute__((ext_vector_type(4)));
typedef float    f32x4 __attribute__((ext_vector_type(4)));
typedef unsigned int u32;
typedef unsigned int u32x2v __attribute__((ext_vector_type(2)));

#define NS 2048
#define NH 16
#define NDK 8
#define NE 128
#define CHUNK 512
#define NCHUNK 4
// log2(e)/sqrt(8): exp(dot/sqrt(8)) == exp2(dot * CSCALE)
#define CSCALE 0.51006972f
#define ONE2 0x3C003C00u

__device__ __forceinline__ float fexp2(float v){
#if __has_builtin(__builtin_amdgcn_exp2f)
  return __builtin_amdgcn_exp2f(v);
#else
  return exp2f(v);
#endif
}

__device__ __forceinline__ f16x2 pkrtz(float a, float b){
  return __builtin_bit_cast(f16x2, __builtin_amdgcn_cvt_pkrtz(a, b));
}

__device__ __forceinline__ float fdot2a(f16x2 a, f16x2 b, float c){
#if __has_builtin(__builtin_amdgcn_fdot2)
  return __builtin_amdgcn_fdot2(a, b, c, false);
#else
  return c + (float)a[0]*(float)b[0] + (float)a[1]*(float)b[1];
#endif
}

// async global->LDS, 16B per lane, dest = wave-uniform base + lane*16
#define GLOAD16(g, l) __builtin_amdgcn_global_load_lds( \
    (const __attribute__((address_space(1))) u32*)(g), \
    (__attribute__((address_space(3))) u32*)(l), 16, 0, 0)

// ---------------------------------------------------------------------------
// qcos: compute cos(x+theta) once, emit TWO f16 layouts:
//  kbuf[(b*16+h)*2048 + s]       : 16B per key (K-layout; also Q source)
//  vbuf[bh][tile t][d][gp][j]    : 16B granules; byte off within 256B tile
//                                  = d*32 + gp*16, u16 j = key 16t+8gp+j
// Block = one (b, tile): 256 thr = 16 keys x 16 heads; LDS transpose.
// ---------------------------------------------------------------------------
__global__ __launch_bounds__(256) void qcos(const float* __restrict__ x,
                                            const float* __restrict__ theta,
                                            u32* __restrict__ kbuf,
                                            u32* __restrict__ vbuf){
  __shared__ __align__(16) uint4 Lt[16*17];   // [h][sl] pad 17 vs bank hits
  const int bid = blockIdx.x;
  const int b   = bid >> 7;
  const int t   = bid & 127;
  const int tid = threadIdx.x;

  const float4 thA = ((const float4*)theta)[0];
  const float4 thB = ((const float4*)theta)[1];

  // phase 1: key s = 16t + sl, head h -> 8 f16
  {
    const int sl = tid & 15, h = tid >> 4;
    const int s  = t*16 + sl;
    const float* xp = x + ((size_t)(b*NS + s)*NE + h*NDK);
    const float4 x0 = ((const float4*)xp)[0];
    const float4 x1 = ((const float4*)xp)[1];
    union { f16 hh[8]; uint4 u; } pk;
    pk.hh[0] = (f16)__cosf(x0.x + thA.x);
    pk.hh[1] = (f16)__cosf(x0.y + thA.y);
    pk.hh[2] = (f16)__cosf(x0.z + thA.z);
    pk.hh[3] = (f16)__cosf(x0.w + thA.w);
    pk.hh[4] = (f16)__cosf(x1.x + thB.x);
    pk.hh[5] = (f16)__cosf(x1.y + thB.y);
    pk.hh[6] = (f16)__cosf(x1.z + thB.z);
    pk.hh[7] = (f16)__cosf(x1.w + thB.w);
    ((uint4*)kbuf)[(size_t)(b*16 + h)*NS + s] = pk.u;
    Lt[h*17 + sl] = pk.u;
  }
  __syncthreads();

  // phase 2: V-tile layout. thread -> (h, d, gp): 16B = keys 8gp..8gp+7 @ dim d
  {
    const int h  = tid >> 4;
    const int d  = (tid >> 1) & 7;
    const int gp = tid & 1;
    const unsigned short* Ls = (const unsigned short*)Lt;
    union { unsigned short us[8]; uint4 u; } pk;
    #pragma unroll
    for(int j = 0; j < 8; ++j)
      pk.us[j] = Ls[(h*17 + 8*gp + j)*8 + d];
    ((uint4*)vbuf)[((size_t)(b*16 + h)*128 + t)*16 + d*2 + gp] = pk.u;
  }
}

// one 16-key tile, shared K/V reads feeding TWO Q-sub-fragments.
// V read by ALL lanes (c>=8 broadcast-aliases c-8); rows>=8 become f16 1.0
// via cndmask -> accumulator row 8 = softmax denominator.
#define QTILE(T, VPO, KPO, ACCA, ACCB) do{ \
    uint2 ka_ = (KPO)[(T)*32]; \
    uint2 va_ = (VPO)[(T)*32]; \
    u32 w0_ = creal ? va_.x : ONE2; \
    u32 w1_ = creal ? va_.y : ONE2; \
    u32x2v vu_ = { w0_, w1_ }; \
    f16x4 kf_ = __builtin_bit_cast(f16x4, ka_); \
    f16x4 vf_ = __builtin_bit_cast(f16x4, vu_); \
    f32x4 s0_ = __builtin_amdgcn_mfma_f32_16x16x16f16(kf_, qf0, z4, 0, 0, 0); \
    f32x4 s1_ = __builtin_amdgcn_mfma_f32_16x16x16f16(kf_, qf1, z4, 0, 0, 0); \
    f16x2 a0_ = pkrtz(fexp2(s0_[0]), fexp2(s0_[1])); \
    f16x2 b0_ = pkrtz(fexp2(s0_[2]), fexp2(s0_[3])); \
    f16x2 a1_ = pkrtz(fexp2(s1_[0]), fexp2(s1_[1])); \
    f16x2 b1_ = pkrtz(fexp2(s1_[2]), fexp2(s1_[3])); \
    u32x2v p0_ = { __builtin_bit_cast(u32, a0_), __builtin_bit_cast(u32, b0_) }; \
    u32x2v p1_ = { __builtin_bit_cast(u32, a1_), __builtin_bit_cast(u32, b1_) }; \
    ACCA = __builtin_amdgcn_mfma_f32_16x16x16f16(vf_, __builtin_bit_cast(f16x4, p0_), ACCA, 0, 0, 0); \
    ACCB = __builtin_amdgcn_mfma_f32_16x16x16f16(vf_, __builtin_bit_cast(f16x4, p1_), ACCB, 0, 0, 0); \
  }while(0)

// ---------------------------------------------------------------------------
// qattn: grid 512 = 64 (b,h) x 8 q-chunks of 256 rows; 512 thr (8 waves x
// 32 q-rows = 2 sub-fragments). Each K/V LDS read is shared by both subs
// (halves LDS-pipe load vs 1 sub). K/V streamed in 512-key chunks, double-
// buffered, staged via global_load_lds width-16 linearly (vbuf already in
// fragment order). 32KB LDS -> 2 blocks/CU, 16 waves/CU.
// ---------------------------------------------------------------------------
__global__ __launch_bounds__(512, 4) void qattn(const u32* __restrict__ kbuf,
                                                const u32* __restrict__ vbuf,
                                                float* __restrict__ out){
  __shared__ __align__(16) u32 Kc[2][2048];     // 2 x 8KB linear [key][16B]
  __shared__ __align__(16) u32 Vt[2][2048];     // 2 x 8KB tile-granule layout

  const int bid  = blockIdx.x;
  const int bh   = bid >> 3;        // 0..63
  const int qc   = bid & 7;         // q-chunk of 256 rows
  const int tid  = threadIdx.x;
  const int lane = tid & 63;
  const int w    = tid >> 6;        // wave 0..7
  const int c    = lane & 15;
  const int grp  = lane >> 4;       // 0..3
  const int g1   = grp & 1;
  const bool lo32  = lane < 32;
  const bool creal = c < 8;

  const u32* kb = kbuf + (size_t)bh*8192;    // 2048 keys x 16B
  const u32* vb = vbuf + (size_t)bh*8192;    // 128 tiles x 256B

  // ---- staging sources: linear, 16B per thread ----
  const u32* gk = kb + (size_t)tid*4;
  const u32* gv = vb + (size_t)tid*4;

  // ---- Q fragments: rows qc*256 + w*32 + {0,16} + c, scaled by CSCALE ----
  const int qrow0 = qc*256 + w*32 + c;
  const int qrow1 = qrow0 + 16;
  uint2 qv0 = make_uint2(0u, 0u), qv1 = make_uint2(0u, 0u);
  if(lo32){
    qv0 = *(const uint2*)(kb + (size_t)qrow0*4 + g1*2);
    qv1 = *(const uint2*)(kb + (size_t)qrow1*4 + g1*2);
  }
  f16x4 q40 = __builtin_bit_cast(f16x4, qv0);
  f16x4 q41 = __builtin_bit_cast(f16x4, qv1);
  q40 *= (f16)CSCALE;
  q41 *= (f16)CSCALE;
  const f16x4 qf0 = q40, qf1 = q41;

  // per-lane V read base (byte offset within a 256B tile): d*32 + grp*8
  const u32 vlane = ((u32)(c & 7))*32u + ((u32)grp)*8u;

  const f32x4 z4 = {0.f, 0.f, 0.f, 0.f};
  f32x4 accA0 = z4, accB0 = z4;    // sub0: even/odd tiles
  f32x4 accA1 = z4, accB1 = z4;    // sub1

  // prologue: issue chunk 0 loads (each wave stages 1KB per buffer)
  GLOAD16(gk, &Kc[0][w*256]);
  GLOAD16(gv, &Vt[0][w*256]);

  for(int cc = 0; cc < NCHUNK; ++cc){
    __syncthreads();   // drains vmcnt(0), then barrier: chunk cc ready
    if(cc + 1 < NCHUNK){
      GLOAD16(gk + (size_t)(cc+1)*2048, &Kc[(cc+1)&1][w*256]);
      GLOAD16(gv + (size_t)(cc+1)*2048, &Vt[(cc+1)&1][w*256]);
    }
    const uint2* kp = (const uint2*)&Kc[cc&1][0] + c*2 + g1;
    const uint2* vp = (const uint2*)((const char*)&Vt[cc&1][0] + vlane);
    #pragma unroll
    for(int o = 0; o < 4; ++o){                       // 4 octets of 8 tiles
      const uint2* kpo = kp + o*256;
      const uint2* vpo = vp + o*256;
      QTILE(0, vpo, kpo, accA0, accA1);
      QTILE(1, vpo, kpo, accB0, accB1);
      QTILE(2, vpo, kpo, accA0, accA1);
      QTILE(3, vpo, kpo, accB0, accB1);
      QTILE(4, vpo, kpo, accA0, accA1);
      QTILE(5, vpo, kpo, accB0, accB1);
      QTILE(6, vpo, kpo, accA0, accA1);
      QTILE(7, vpo, kpo, accB0, accB1);
    }
  }

  // ---- epilogue: acc row 8 (lane 32+c, reg 0) = denominator ----
  const int b = bh >> 4, h = bh & 15;
  {
    f32x4 aT;
    aT[0]=accA0[0]+accB0[0]; aT[1]=accA0[1]+accB0[1];
    aT[2]=accA0[2]+accB0[2]; aT[3]=accA0[3]+accB0[3];
    float den = __shfl(aT[0], 32 + c, 64);
    if(lo32){
      float inv = 1.0f / den;
      float4 o;
      o.x = aT[0]*inv; o.y = aT[1]*inv; o.z = aT[2]*inv; o.w = aT[3]*inv;
      *(float4*)(out + ((size_t)(b*NS + qrow0)*NH + h)*NDK + grp*4) = o;
    }
  }
  {
    f32x4 aT;
    aT[0]=accA1[0]+accB1[0]; aT[1]=accA1[1]+accB1[1];
    aT[2]=accA1[2]+accB1[2]; aT[3]=accA1[3]+accB1[3];
    float den = __shfl(aT[0], 32 + c, 64);
    if(lo32){
      float inv = 1.0f / den;
      float4 o;
      o.x = aT[0]*inv; o.y = aT[1]*inv; o.z = aT[2]*inv; o.w = aT[3]*inv;
      *(float4*)(out + ((size_t)(b*NS + qrow1)*NH + h)*NDK + grp*4) = o;
    }
  }
}

// ---------------------------------------------------------------------------
// Combine: out = attn @ W^T + bias, in-place on d_out (unchanged).
// ---------------------------------------------------------------------------
__global__ __launch_bounds__(256) void qcomb(const float* __restrict__ W,
                                             const float* __restrict__ bias,
                                             float* __restrict__ io){
  __shared__ __align__(16) u32 Wt[64*132];
  __shared__ __align__(16) u32 A2[32*65];
  const int tid = threadIdx.x;
  const size_t row0 = (size_t)blockIdx.x * 32;

  #pragma unroll
  for(int i=0;i<32;++i){
    int g = tid + 256*i;
    int j = g >> 6, e2 = g & 63;
    const float* wp = W + (size_t)j*NE + 2*e2;
    f16x2 wv = pkrtz(wp[0], wp[1]);
    Wt[e2*132 + j] = __builtin_bit_cast(u32, wv);
  }
  #pragma unroll
  for(int i=0;i<8;++i){
    int g = tid + 256*i;
    int r = g >> 6, e2 = g & 63;
    const float* ap = io + (row0 + r)*NE + 2*e2;
    f16x2 av = pkrtz(ap[0], ap[1]);
    A2[r*65 + e2] = __builtin_bit_cast(u32, av);
  }
  __syncthreads();

  const int tr = tid >> 4, tc = tid & 15;
  float acc0[8] = {0,0,0,0,0,0,0,0};
  float acc1[8] = {0,0,0,0,0,0,0,0};
  for(int e2=0; e2<64; ++e2){
    f16x2 a0 = __builtin_bit_cast(f16x2, A2[tr*65 + e2]);
    f16x2 a1 = __builtin_bit_cast(f16x2, A2[(tr+16)*65 + e2]);
    const u32* wr = &Wt[e2*132 + tc*8];
    #pragma unroll
    for(int cj=0; cj<8; ++cj){
      f16x2 wv = __builtin_bit_cast(f16x2, wr[cj]);
      acc0[cj] = fdot2a(a0, wv, acc0[cj]);
      acc1[cj] = fdot2a(a1, wv, acc1[cj]);
    }
  }

  float4 b0 = *(const float4*)(bias + tc*8);
  float4 b1 = *(const float4*)(bias + tc*8 + 4);
  float* o0 = io + (row0 + tr)*NE + tc*8;
  float* o1 = io + (row0 + tr + 16)*NE + tc*8;
  float4 v;
  v.x = acc0[0]+b0.x; v.y = acc0[1]+b0.y; v.z = acc0[2]+b0.z; v.w = acc0[3]+b0.w;
  *(float4*)(o0) = v;
  v.x = acc0[4]+b1.x; v.y = acc0[5]+b1.y; v.z = acc0[6]+b1.z; v.w = acc0[7]+b1.w;
  *(float4*)(o0+4) = v;
  v.x = acc1[0]+b0.x; v.y = acc1[1]+b0.y; v.z = acc1[2]+b0.z; v.w = acc1[3]+b0.w;
  *(float4*)(o1) = v;
  v.x = acc1[4]+b1.x; v.y = acc1[5]+b1.y; v.z = acc1[6]+b1.z; v.w = acc1[7]+b1.w;
  *(float4*)(o1+4) = v;
}

extern "C" void kernel_launch(void* const* d_in, const int* in_sizes, int n_in,
                              void* d_out, int out_size, void* d_ws, size_t ws_size,
                              hipStream_t stream) {
  (void)in_sizes; (void)n_in; (void)out_size; (void)ws_size;
  const float* x     = (const float*)d_in[0];
  const float* theta = (const float*)d_in[1];
  const float* W     = (const float*)d_in[2];
  const float* bias  = (const float*)d_in[3];
  float* out = (float*)d_out;
  u32* kbuf = (u32*)d_ws;            // 2MB: K/Q layout [bh][s][8 f16]
  u32* vbuf = kbuf + 524288;         // 2MB: V tile-granule layout

  qcos <<<512, 256, 0, stream>>>(x, theta, kbuf, vbuf);
  qattn<<<512, 512, 0, stream>>>(kbuf, vbuf, out);
  qcomb<<<256, 256, 0, stream>>>(W, bias, out);
}

// Round 10
// 50.855 us; speedup vs baseline: 1.0560x; 1.0039x over previous
//
#include <hip/hip_runtime.h>

typedef _Float16 f16;
typedef _Float16 f16x2 __attribute__((ext_vector_type(2)));
typedef _Float16 f16x4 __attribute__((ext_vector_type(4)));
typedef float    f32x4 __attribute__((ext_vector_type(4)));
typedef unsigned int u32;
typedef unsigned int u32x2v __attribute__((ext_vector_type(2)));

#define NS 2048
#define NH 16
#define NDK 8
#define NE 128
#define CHUNK 512
#define NCHUNK 4
// log2(e)/sqrt(8): exp(dot/sqrt(8)) == exp2(dot * CSCALE)
#define CSCALE 0.51006972f
#define ONE2 0x3C003C00u

__device__ __forceinline__ float fexp2(float v){
#if __has_builtin(__builtin_amdgcn_exp2f)
  return __builtin_amdgcn_exp2f(v);
#else
  return exp2f(v);
#endif
}

__device__ __forceinline__ f16x2 pkrtz(float a, float b){
  return __builtin_bit_cast(f16x2, __builtin_amdgcn_cvt_pkrtz(a, b));
}

__device__ __forceinline__ float fdot2a(f16x2 a, f16x2 b, float c){
#if __has_builtin(__builtin_amdgcn_fdot2)
  return __builtin_amdgcn_fdot2(a, b, c, false);
#else
  return c + (float)a[0]*(float)b[0] + (float)a[1]*(float)b[1];
#endif
}

// async global->LDS, 16B per lane, dest = wave-uniform base + lane*16
#define GLOAD16(g, l) __builtin_amdgcn_global_load_lds( \
    (const __attribute__((address_space(1))) u32*)(g), \
    (__attribute__((address_space(3))) u32*)(l), 16, 0, 0)

// ---------------------------------------------------------------------------
// qcos: compute cos(x+theta) once, emit TWO f16 layouts:
//  kbuf[(b*16+h)*2048 + s]    : 16B per key (K-layout; also Q source)
//  vbuf[bh][tile t][slot]     : 16B granules; granule (d,gp) (= keys
//    16t+8gp..+7 at dim d) stored at slot d*2 + (gp ^ ((d>>2)&1))
//    -> the gp-XOR spreads V reads across all 32 banks (conflict-free).
// Block = one (b, tile): 256 thr = 16 keys x 16 heads; LDS transpose.
// ---------------------------------------------------------------------------
__global__ __launch_bounds__(256) void qcos(const float* __restrict__ x,
                                            const float* __restrict__ theta,
                                            u32* __restrict__ kbuf,
                                            u32* __restrict__ vbuf){
  __shared__ __align__(16) uint4 Lt[16*17];   // [h][sl] pad 17 vs bank hits
  const int bid = blockIdx.x;
  const int b   = bid >> 7;
  const int t   = bid & 127;
  const int tid = threadIdx.x;

  const float4 thA = ((const float4*)theta)[0];
  const float4 thB = ((const float4*)theta)[1];

  // phase 1: key s = 16t + sl, head h -> 8 f16
  {
    const int sl = tid & 15, h = tid >> 4;
    const int s  = t*16 + sl;
    const float* xp = x + ((size_t)(b*NS + s)*NE + h*NDK);
    const float4 x0 = ((const float4*)xp)[0];
    const float4 x1 = ((const float4*)xp)[1];
    union { f16 hh[8]; uint4 u; } pk;
    pk.hh[0] = (f16)__cosf(x0.x + thA.x);
    pk.hh[1] = (f16)__cosf(x0.y + thA.y);
    pk.hh[2] = (f16)__cosf(x0.z + thA.z);
    pk.hh[3] = (f16)__cosf(x0.w + thA.w);
    pk.hh[4] = (f16)__cosf(x1.x + thB.x);
    pk.hh[5] = (f16)__cosf(x1.y + thB.y);
    pk.hh[6] = (f16)__cosf(x1.z + thB.z);
    pk.hh[7] = (f16)__cosf(x1.w + thB.w);
    ((uint4*)kbuf)[(size_t)(b*16 + h)*NS + s] = pk.u;
    Lt[h*17 + sl] = pk.u;
  }
  __syncthreads();

  // phase 2: V-tile layout. thread -> (h, d, gp): 16B = keys 8gp..8gp+7 @ dim d
  {
    const int h  = tid >> 4;
    const int d  = (tid >> 1) & 7;
    const int gp = tid & 1;
    const unsigned short* Ls = (const unsigned short*)Lt;
    union { unsigned short us[8]; uint4 u; } pk;
    #pragma unroll
    for(int j = 0; j < 8; ++j)
      pk.us[j] = Ls[(h*17 + 8*gp + j)*8 + d];
    const int slot = d*2 + (gp ^ ((d >> 2) & 1));   // bank-spread XOR
    ((uint4*)vbuf)[((size_t)(b*16 + h)*128 + t)*16 + slot] = pk.u;
  }
}

// one 16-key tile from preloaded values; K/V shared by TWO Q-sub-fragments.
// V read by all lanes (c>=8 broadcast-aliases c-8); rows>=8 become f16 1.0
// via cndmask -> accumulator row 8 = softmax denominator.
#define QCOMP(KA, VA, ACCA, ACCB) do{ \
    u32 w0_ = creal ? (VA).x : ONE2; \
    u32 w1_ = creal ? (VA).y : ONE2; \
    u32x2v vu_ = { w0_, w1_ }; \
    f16x4 kf_ = __builtin_bit_cast(f16x4, (KA)); \
    f16x4 vf_ = __builtin_bit_cast(f16x4, vu_); \
    f32x4 s0_ = __builtin_amdgcn_mfma_f32_16x16x16f16(kf_, qf0, z4, 0, 0, 0); \
    f32x4 s1_ = __builtin_amdgcn_mfma_f32_16x16x16f16(kf_, qf1, z4, 0, 0, 0); \
    f16x2 a0_ = pkrtz(fexp2(s0_[0]), fexp2(s0_[1])); \
    f16x2 b0_ = pkrtz(fexp2(s0_[2]), fexp2(s0_[3])); \
    f16x2 a1_ = pkrtz(fexp2(s1_[0]), fexp2(s1_[1])); \
    f16x2 b1_ = pkrtz(fexp2(s1_[2]), fexp2(s1_[3])); \
    u32x2v p0_ = { __builtin_bit_cast(u32, a0_), __builtin_bit_cast(u32, b0_) }; \
    u32x2v p1_ = { __builtin_bit_cast(u32, a1_), __builtin_bit_cast(u32, b1_) }; \
    ACCA = __builtin_amdgcn_mfma_f32_16x16x16f16(vf_, __builtin_bit_cast(f16x4, p0_), ACCA, 0, 0, 0); \
    ACCB = __builtin_amdgcn_mfma_f32_16x16x16f16(vf_, __builtin_bit_cast(f16x4, p1_), ACCB, 0, 0, 0); \
  }while(0)

// prefetch tile T+1 into (kn,vn), compute tile T from (ka,va), shift
#define QSTEP(TN, ACCA, ACCB) do{ \
    uint2 kn_ = kpo[(TN)*32]; \
    uint2 vn_ = vpo[(TN)*32]; \
    QCOMP(ka, va, ACCA, ACCB); \
    ka = kn_; va = vn_; \
  }while(0)

// ---------------------------------------------------------------------------
// qattn: grid 512 = 64 (b,h) x 8 q-chunks of 256 rows; 512 thr (8 waves x
// 32 q-rows = 2 sub-fragments sharing each K/V read). K/V streamed in
// 512-key chunks, double-buffered, staged linearly via global_load_lds.
// Inner loop is software-pipelined (1-tile register prefetch) so ds_reads
// overlap the exp2/MFMA work, and each wave starts at octet (w&3) so the
// 8 waves' LDS/trans demand interleaves instead of bursting in lockstep.
// 32KB LDS -> 2 blocks/CU = 16 waves/CU = 4/SIMD.
// ---------------------------------------------------------------------------
__global__ __launch_bounds__(512, 4) void qattn(const u32* __restrict__ kbuf,
                                                const u32* __restrict__ vbuf,
                                                float* __restrict__ out){
  __shared__ __align__(16) u32 Kc[2][2048];     // 2 x 8KB linear [key][16B]
  __shared__ __align__(16) u32 Vt[2][2048];     // 2 x 8KB tile-granule layout

  const int bid  = blockIdx.x;
  const int bh   = bid >> 3;        // 0..63
  const int qc   = bid & 7;         // q-chunk of 256 rows
  const int tid  = threadIdx.x;
  const int lane = tid & 63;
  const int w    = tid >> 6;        // wave 0..7
  const int c    = lane & 15;
  const int grp  = lane >> 4;       // 0..3
  const int g1   = grp & 1;
  const bool lo32  = lane < 32;
  const bool creal = c < 8;

  const u32* kb = kbuf + (size_t)bh*8192;    // 2048 keys x 16B
  const u32* vb = vbuf + (size_t)bh*8192;    // 128 tiles x 256B

  // ---- staging sources: linear, 16B per thread ----
  const u32* gk = kb + (size_t)tid*4;
  const u32* gv = vb + (size_t)tid*4;

  // ---- Q fragments: rows qc*256 + w*32 + {0,16} + c, scaled by CSCALE ----
  const int qrow0 = qc*256 + w*32 + c;
  const int qrow1 = qrow0 + 16;
  uint2 qv0 = make_uint2(0u, 0u), qv1 = make_uint2(0u, 0u);
  if(lo32){
    qv0 = *(const uint2*)(kb + (size_t)qrow0*4 + g1*2);
    qv1 = *(const uint2*)(kb + (size_t)qrow1*4 + g1*2);
  }
  f16x4 q40 = __builtin_bit_cast(f16x4, qv0);
  f16x4 q41 = __builtin_bit_cast(f16x4, qv1);
  q40 *= (f16)CSCALE;
  q41 *= (f16)CSCALE;
  const f16x4 qf0 = q40, qf1 = q41;

  // per-lane V read base within a 256B tile (matches qcos slot XOR):
  // byte = d*32 + ((grp>>1)^((c>>2)&1))*16 + (grp&1)*8
  const u32 vlane = ((u32)(c & 7))*32u
                  + (u32)((((grp >> 1) ^ ((c >> 2) & 1)))*16)
                  + ((u32)(grp & 1))*8u;

  const f32x4 z4 = {0.f, 0.f, 0.f, 0.f};
  f32x4 accA0 = z4, accB0 = z4;    // sub0: even/odd tiles
  f32x4 accA1 = z4, accB1 = z4;    // sub1

  // prologue: issue chunk 0 loads (each wave stages 1KB per buffer)
  GLOAD16(gk, &Kc[0][w*256]);
  GLOAD16(gv, &Vt[0][w*256]);

  for(int cc = 0; cc < NCHUNK; ++cc){
    __syncthreads();   // drains vmcnt(0), then barrier: chunk cc ready
    if(cc + 1 < NCHUNK){
      GLOAD16(gk + (size_t)(cc+1)*2048, &Kc[(cc+1)&1][w*256]);
      GLOAD16(gv + (size_t)(cc+1)*2048, &Vt[(cc+1)&1][w*256]);
    }
    const uint2* kp = (const uint2*)&Kc[cc&1][0] + c*2 + g1;
    const uint2* vp = (const uint2*)((const char*)&Vt[cc&1][0] + vlane);
    #pragma unroll
    for(int oo = 0; oo < 4; ++oo){               // wave-rotated octet order
      const int o = (oo + w) & 3;
      const uint2* kpo = kp + o*256;
      const uint2* vpo = vp + o*256;
      uint2 ka = kpo[0], va = vpo[0];
      QSTEP(1, accA0, accA1);
      QSTEP(2, accB0, accB1);
      QSTEP(3, accA0, accA1);
      QSTEP(4, accB0, accB1);
      QSTEP(5, accA0, accA1);
      QSTEP(6, accB0, accB1);
      QSTEP(7, accA0, accA1);
      QCOMP(ka, va, accB0, accB1);               // tile 7 (no prefetch)
    }
  }

  // ---- epilogue: acc row 8 (lane 32+c, reg 0) = denominator ----
  const int b = bh >> 4, h = bh & 15;
  {
    f32x4 aT;
    aT[0]=accA0[0]+accB0[0]; aT[1]=accA0[1]+accB0[1];
    aT[2]=accA0[2]+accB0[2]; aT[3]=accA0[3]+accB0[3];
    float den = __shfl(aT[0], 32 + c, 64);
    if(lo32){
      float inv = 1.0f / den;
      float4 o;
      o.x = aT[0]*inv; o.y = aT[1]*inv; o.z = aT[2]*inv; o.w = aT[3]*inv;
      *(float4*)(out + ((size_t)(b*NS + qrow0)*NH + h)*NDK + grp*4) = o;
    }
  }
  {
    f32x4 aT;
    aT[0]=accA1[0]+accB1[0]; aT[1]=accA1[1]+accB1[1];
    aT[2]=accA1[2]+accB1[2]; aT[3]=accA1[3]+accB1[3];
    float den = __shfl(aT[0], 32 + c, 64);
    if(lo32){
      float inv = 1.0f / den;
      float4 o;
      o.x = aT[0]*inv; o.y = aT[1]*inv; o.z = aT[2]*inv; o.w = aT[3]*inv;
      *(float4*)(out + ((size_t)(b*NS + qrow1)*NH + h)*NDK + grp*4) = o;
    }
  }
}

// ---------------------------------------------------------------------------
// Combine: out = attn @ W^T + bias, in-place on d_out (unchanged).
// ---------------------------------------------------------------------------
__global__ __launch_bounds__(256) void qcomb(const float* __restrict__ W,
                                             const float* __restrict__ bias,
                                             float* __restrict__ io){
  __shared__ __align__(16) u32 Wt[64*132];
  __shared__ __align__(16) u32 A2[32*65];
  const int tid = threadIdx.x;
  const size_t row0 = (size_t)blockIdx.x * 32;

  #pragma unroll
  for(int i=0;i<32;++i){
    int g = tid + 256*i;
    int j = g >> 6, e2 = g & 63;
    const float* wp = W + (size_t)j*NE + 2*e2;
    f16x2 wv = pkrtz(wp[0], wp[1]);
    Wt[e2*132 + j] = __builtin_bit_cast(u32, wv);
  }
  #pragma unroll
  for(int i=0;i<8;++i){
    int g = tid + 256*i;
    int r = g >> 6, e2 = g & 63;
    const float* ap = io + (row0 + r)*NE + 2*e2;
    f16x2 av = pkrtz(ap[0], ap[1]);
    A2[r*65 + e2] = __builtin_bit_cast(u32, av);
  }
  __syncthreads();

  const int tr = tid >> 4, tc = tid & 15;
  float acc0[8] = {0,0,0,0,0,0,0,0};
  float acc1[8] = {0,0,0,0,0,0,0,0};
  for(int e2=0; e2<64; ++e2){
    f16x2 a0 = __builtin_bit_cast(f16x2, A2[tr*65 + e2]);
    f16x2 a1 = __builtin_bit_cast(f16x2, A2[(tr+16)*65 + e2]);
    const u32* wr = &Wt[e2*132 + tc*8];
    #pragma unroll
    for(int cj=0; cj<8; ++cj){
      f16x2 wv = __builtin_bit_cast(f16x2, wr[cj]);
      acc0[cj] = fdot2a(a0, wv, acc0[cj]);
      acc1[cj] = fdot2a(a1, wv, acc1[cj]);
    }
  }

  float4 b0 = *(const float4*)(bias + tc*8);
  float4 b1 = *(const float4*)(bias + tc*8 + 4);
  float* o0 = io + (row0 + tr)*NE + tc*8;
  float* o1 = io + (row0 + tr + 16)*NE + tc*8;
  float4 v;
  v.x = acc0[0]+b0.x; v.y = acc0[1]+b0.y; v.z = acc0[2]+b0.z; v.w = acc0[3]+b0.w;
  *(float4*)(o0) = v;
  v.x = acc0[4]+b1.x; v.y = acc0[5]+b1.y; v.z = acc0[6]+b1.z; v.w = acc0[7]+b1.w;
  *(float4*)(o0+4) = v;
  v.x = acc1[0]+b0.x; v.y = acc1[1]+b0.y; v.z = acc1[2]+b0.z; v.w = acc1[3]+b0.w;
  *(float4*)(o1) = v;
  v.x = acc1[4]+b1.x; v.y = acc1[5]+b1.y; v.z = acc1[6]+b1.z; v.w = acc1[7]+b1.w;
  *(float4*)(o1+4) = v;
}

extern "C" void kernel_launch(void* const* d_in, const int* in_sizes, int n_in,
                              void* d_out, int out_size, void* d_ws, size_t ws_size,
                              hipStream_t stream) {
  (void)in_sizes; (void)n_in; (void)out_size; (void)ws_size;
  const float* x     = (const float*)d_in[0];
  const float* theta = (const float*)d_in[1];
  const float* W     = (const float*)d_in[2];
  const float* bias  = (const float*)d_in[3];
  float* out = (float*)d_out;
  u32* kbuf = (u32*)d_ws;            // 2MB: K/Q layout [bh][s][8 f16]
  u32* vbuf = kbuf + 524288;         // 2MB: V tile-granule layout

  qcos <<<512, 256, 0, stream>>>(x, theta, kbuf, vbuf);
  qattn<<<512, 512, 0, stream>>>(kbuf, vbuf, out);
  qcomb<<<256, 256, 0, stream>>>(W, bias, out);
}